// Round 5
// baseline (74.641 us; speedup 1.0000x reference)
//
#include <hip/hip_runtime.h>

// Problem constants (fixed by the reference):
//   B=8, N=256, IN_F=64, OUT_F=64, IN_E=32, OUT_E=64
#define BB    8
#define NN    256
#define OUTF  64
#define INE   32

using f4     = __attribute__((ext_vector_type(4))) float;
using f32x4  = __attribute__((ext_vector_type(4))) float;
using bf16x8 = __attribute__((ext_vector_type(8))) short;          // 8 bf16 = 4 VGPRs
using us4    = __attribute__((ext_vector_type(4))) unsigned short; // 8 B

// Device-global scratch (no ws_size dependence); fully overwritten every call.
__device__ float          g_node_x[BB * NN * OUTF];   // emb_node@W_node + b (pre-relu)
__device__ float          g_relu_sx[BB * NN * OUTF];  // relu(emb_node@W_nodes + b)
__device__ unsigned short g_wtb[OUTF * INE];          // W_edge^T as bf16, [f][k]

// f32 -> bf16 round-to-nearest-even.
static __device__ __forceinline__ unsigned short f2bf(float x) {
    unsigned u = __builtin_bit_cast(unsigned, x);
    u += 0x7fffu + ((u >> 16) & 1u);
    return (unsigned short)(u >> 16);
}

// ---------------------------------------------------------------------------
// Kernel 1: node projections (fp32 VALU — tiny) + one-time W_edge^T bf16 prep.
// ---------------------------------------------------------------------------
__global__ __launch_bounds__(256) void node_proj(
    const float* __restrict__ emb_node,  // [B*N, 64]
    const float* __restrict__ W1, const float* __restrict__ b1,
    const float* __restrict__ W2, const float* __restrict__ b2,
    const float* __restrict__ W_edge)    // [32, 64]
{
    __shared__ float sW1[64][64];
    __shared__ float sW2[64][64];
    __shared__ float sE[4][64];

    const int tid = threadIdx.x;

    if (blockIdx.x == 0) {               // prep W_edge^T bf16 (2 KB)
        const int f  = tid >> 2;
        const int k0 = (tid & 3) * 8;
#pragma unroll
        for (int j = 0; j < 8; ++j)
            g_wtb[f * INE + k0 + j] = f2bf(W_edge[(k0 + j) * OUTF + f]);
    }

    const f4* w1v = (const f4*)W1;
    const f4* w2v = (const f4*)W2;
    f4* s1 = (f4*)&sW1[0][0];
    f4* s2 = (f4*)&sW2[0][0];
#pragma unroll
    for (int i = 0; i < 4; ++i) {
        s1[tid + i * 256] = w1v[tid + i * 256];
        s2[tid + i * 256] = w2v[tid + i * 256];
    }
    const int row0 = blockIdx.x * 4;
    if (tid < 64) ((f4*)&sE[0][0])[tid] = ((const f4*)(emb_node + row0 * 64))[tid];
    __syncthreads();

    const int s = tid >> 6;
    const int f = tid & 63;
    float a1 = b1[f];
    float a2 = b2[f];
#pragma unroll
    for (int k = 0; k < 64; ++k) {
        const float e = sE[s][k];
        a1 = fmaf(e, sW1[k][f], a1);
        a2 = fmaf(e, sW2[k][f], a2);
    }
    const int row = row0 + s;
    g_node_x[row * 64 + f]  = a1;
    g_relu_sx[row * 64 + f] = fmaxf(a2, 0.f);
}

// ---------------------------------------------------------------------------
// Kernel 2: per (b,n) block, 256 threads = 4 waves.
// Identical to R4 EXCEPT the store path: MFMA acc (lane c=m, regs=4 consec f —
// 64B half-line store shape) is transposed through a WAVE-LOCAL LDS buffer to
// the R1-proven full-line shape: store instr = 4 consecutive rows x 256B = 1KB
// of fully-covered 128B cache lines.
//  - wave w owns rows [64w,64w+64); its E-staging slice (64 rows x 80B = 5120B)
//    is dead after efrag[0..3] preload -> reused as transpose buf [16][68] f32
//    (4352B). Per-wave LDS ops are in-order; no barriers in the mt loop.
//  - all LDS patterns (stage b64 writes, efrag b128, transpose b128 w/r) are
//    at the even 8-lanes-per-4-bank-group floor: zero extra conflicts.
//  - agg (needs pre-relu acc) computed in MFMA layout before the transpose.
// ---------------------------------------------------------------------------
__global__ __launch_bounds__(256, 4) void edge_agg(
    const float* __restrict__ A,         // [B,N,N]
    const float* __restrict__ emb_edge,  // [B,N,N,32]
    const float* __restrict__ b_edge,    // [64]
    float* __restrict__ node_out,        // [B,N,64]
    float* __restrict__ edge_out)        // [B,N,N,64]
{
    // 4 wave slices x 5120 B (E rows / transpose buf) + 1 KB reduce buffer.
    __shared__ __align__(16) unsigned char smem[4 * 5120 + 1024];
    unsigned short* sEb  = (unsigned short*)smem;          // row m: m*40 shorts
    float (*sRed)[64]    = (float (*)[64])(smem + 20480);

    const int tid  = threadIdx.x;
    const int bn   = blockIdx.x;             // b*256 + n
    const int b    = bn >> 8;
    const int wave = tid >> 6;
    const int lane = tid & 63;
    const int c    = lane & 15;              // m within 16-tile / f-row of W^T
    const int q    = lane >> 4;              // k-quad & f-quad selector

    // ---- L2-hot fragments (overlap with staging) ----
    bf16x8 wfrag[4];
    f4     bias[4];
#pragma unroll
    for (int ft = 0; ft < 4; ++ft) {
        wfrag[ft] = *(const bf16x8*)&g_wtb[(ft * 16 + c) * INE + q * 8];
        bias[ft]  = *(const f4*)&b_edge[ft * 16 + q * 4];
    }

    // ---- stage E -> bf16 LDS: 2048 f4 chunks, 8 per thread, wave-dense ----
    const f4* embv = (const f4*)(emb_edge + (size_t)bn * (NN * INE));
#pragma unroll
    for (int it = 0; it < 8; ++it) {
        const int i = tid + it * 256;        // row = i>>3, k-quad = i&7
        const f4 v = __builtin_nontemporal_load(embv + i);
        us4 h;
        h.x = f2bf(v.x); h.y = f2bf(v.y); h.z = f2bf(v.z); h.w = f2bf(v.w);
        *(us4*)&sEb[(i >> 3) * 40 + (i & 7) * 4] = h;
    }
    __syncthreads();

    const int wbase = wave * 64;

    // ---- preload ALL E fragments for this wave (frees its LDS slice) ----
    bf16x8 efrag[4];
#pragma unroll
    for (int mt = 0; mt < 4; ++mt)
        efrag[mt] = *(const bf16x8*)&sEb[(wbase + mt * 16 + c) * 40 + q * 8];

    // wave-local transpose buffer over this wave's (now dead) E slice
    float* sT = (float*)(smem + wave * 5120);   // [16][68] f32

    const float* Arow = A + bn * NN;
    const float* nx   = g_node_x + b * (NN * OUTF);
    float*       eo   = edge_out + (size_t)bn * (NN * OUTF);

    f4 agg[4];
#pragma unroll
    for (int ft = 0; ft < 4; ++ft) { agg[ft].x = 0.f; agg[ft].y = 0.f; agg[ft].z = 0.f; agg[ft].w = 0.f; }

#pragma unroll
    for (int mt = 0; mt < 4; ++mt) {
        const int   m = wbase + mt * 16 + c;
        const float a = Arow[m];                               // L1/L2-hot

        f32x4 acc[4];
#pragma unroll
        for (int ft = 0; ft < 4; ++ft)
            acc[ft] = __builtin_amdgcn_mfma_f32_16x16x32_bf16(
                wfrag[ft], efrag[mt], bias[ft], 0, 0, 0);

        // agg in MFMA layout (pre-relu acc), nx reads are L2-hot
#pragma unroll
        for (int ft = 0; ft < 4; ++ft) {
            const int fb  = ft * 16 + q * 4;
            const f4  v   = acc[ft];
            const f4  nxv = *(const f4*)&nx[m * OUTF + fb];
            agg[ft].x = fmaf(a * v.x, nxv.x, agg[ft].x);
            agg[ft].y = fmaf(a * v.y, nxv.y, agg[ft].y);
            agg[ft].z = fmaf(a * v.z, nxv.z, agg[ft].z);
            agg[ft].w = fmaf(a * v.w, nxv.w, agg[ft].w);
        }

        // transpose in: lane (c,q) writes acc[ft] at logical (row c, f4-chunk ft*4+q)
#pragma unroll
        for (int ft = 0; ft < 4; ++ft)
            *(f4*)&sT[c * 68 + (ft * 4 + q) * 4] = acc[ft];

        // transpose out + relu + FULL-LINE nt stores:
        // lane l -> (row g*4 + (l>>4), f4-chunk l&15); instr = 4 rows x 256B.
        const int rsub = lane >> 4;
        const int fc   = lane & 15;
#pragma unroll
        for (int g = 0; g < 4; ++g) {
            const int rloc = g * 4 + rsub;
            f4 v = *(const f4*)&sT[rloc * 68 + fc * 4];
            v.x = fmaxf(v.x, 0.f); v.y = fmaxf(v.y, 0.f);
            v.z = fmaxf(v.z, 0.f); v.w = fmaxf(v.w, 0.f);
            const int mrow = wbase + mt * 16 + rloc;
            __builtin_nontemporal_store(v, (f4*)&eo[(size_t)mrow * OUTF + fc * 4]);
        }
        // keep compiler from hoisting next mt's LDS writes over these reads
        __builtin_amdgcn_sched_barrier(0);
    }

    // ---- reduce over the 16 m-columns (lane bits 0..3 == c) ----
#pragma unroll
    for (int ft = 0; ft < 4; ++ft) {
#pragma unroll
        for (int s = 1; s < 16; s <<= 1) {
            agg[ft].x += __shfl_xor(agg[ft].x, s);
            agg[ft].y += __shfl_xor(agg[ft].y, s);
            agg[ft].z += __shfl_xor(agg[ft].z, s);
            agg[ft].w += __shfl_xor(agg[ft].w, s);
        }
    }
    if (c == 0) {
#pragma unroll
        for (int ft = 0; ft < 4; ++ft)
            *(f4*)&sRed[wave][ft * 16 + q * 4] = agg[ft];
    }
    __syncthreads();

    // ---- reduce across 4 waves, add relu(node_sx), store node_out ----
    if (tid < 64) {
        float s = sRed[0][tid] + sRed[1][tid] + sRed[2][tid] + sRed[3][tid];
        node_out[bn * OUTF + tid] = fmaxf(s, 0.f) + g_relu_sx[bn * OUTF + tid];
    }
}

// ---------------------------------------------------------------------------
extern "C" void kernel_launch(void* const* d_in, const int* in_sizes, int n_in,
                              void* d_out, int out_size, void* d_ws, size_t ws_size,
                              hipStream_t stream) {
    const float* A        = (const float*)d_in[0];
    const float* emb_node = (const float*)d_in[1];
    const float* emb_edge = (const float*)d_in[2];
    const float* W_node   = (const float*)d_in[3];
    const float* b_node   = (const float*)d_in[4];
    const float* W_nodes  = (const float*)d_in[5];
    const float* b_nodes  = (const float*)d_in[6];
    const float* W_edge   = (const float*)d_in[7];
    const float* b_edge   = (const float*)d_in[8];

    float* node_out = (float*)d_out;                 // [8,256,64]
    float* edge_out = node_out + BB * NN * OUTF;     // [8,256,256,64]

    node_proj<<<(BB * NN) / 4, 256, 0, stream>>>(emb_node, W_node, b_node,
                                                 W_nodes, b_nodes, W_edge);
    edge_agg<<<BB * NN, 256, 0, stream>>>(A, emb_edge, b_edge, node_out, edge_out);
}

// Round 6
// 52.809 us; speedup vs baseline: 1.4134x; 1.4134x over previous
//
#include <hip/hip_runtime.h>

// Problem constants (fixed by the reference):
//   B=8, N=256, IN_F=64, OUT_F=64, IN_E=32, OUT_E=64
#define BB    8
#define NN    256
#define OUTF  64
#define INE   32

using f4 = __attribute__((ext_vector_type(4))) float;

// Scratch for the node projections (1 MB total) — device globals so we do not
// depend on ws_size. Fully overwritten by node_proj every call (deterministic).
__device__ float g_node_x[BB * NN * OUTF];   // emb_node@W_node + b_node (pre-relu)
__device__ float g_relu_sx[BB * NN * OUTF];  // relu(emb_node@W_nodes + b_nodes)

// ---------------------------------------------------------------------------
// Kernel 1: node projections. 512 blocks x 256 threads, 4 rows per block.
// (identical to the R1 champion, minus the unused W_edge prep)
// ---------------------------------------------------------------------------
__global__ __launch_bounds__(256) void node_proj(
    const float* __restrict__ emb_node,  // [B*N, 64]
    const float* __restrict__ W1, const float* __restrict__ b1,
    const float* __restrict__ W2, const float* __restrict__ b2)
{
    __shared__ float sW1[64][64];
    __shared__ float sW2[64][64];
    __shared__ float sE[4][64];

    const int tid = threadIdx.x;

    const f4* w1v = (const f4*)W1;
    const f4* w2v = (const f4*)W2;
    f4* s1 = (f4*)&sW1[0][0];
    f4* s2 = (f4*)&sW2[0][0];
#pragma unroll
    for (int i = 0; i < 4; ++i) {
        s1[tid + i * 256] = w1v[tid + i * 256];
        s2[tid + i * 256] = w2v[tid + i * 256];
    }
    const int row0 = blockIdx.x * 4;
    if (tid < 64) ((f4*)&sE[0][0])[tid] = ((const f4*)(emb_node + row0 * 64))[tid];
    __syncthreads();

    const int s = tid >> 6;    // row within block (0..3)
    const int f = tid & 63;    // output feature
    float a1 = b1[f];
    float a2 = b2[f];
#pragma unroll
    for (int k = 0; k < 64; ++k) {
        const float e = sE[s][k];              // broadcast read
        a1 = fmaf(e, sW1[k][f], a1);
        a2 = fmaf(e, sW2[k][f], a2);
    }
    const int row = row0 + s;
    g_node_x[row * 64 + f]  = a1;              // pre-relu (used inside einsum)
    g_relu_sx[row * 64 + f] = fmaxf(a2, 0.f);
}

// ---------------------------------------------------------------------------
// Kernel 2: the R1 champion body (register-tiled fp32 VALU GEMM, identical
// global/LDS memory patterns) with TWO residency changes:
//   1. sRed is UNIONed onto sW (sW is dead after the GEMM loop; one extra
//      __syncthreads() fences the alias).  LDS: 54272 -> 46080 B => 3 blk/CU.
//   2. inner loop holds w[4] per k-chunk (transient) instead of ev[8]:
//      peak live ~60-65 VGPR; __launch_bounds__(512,6) caps at ~84 so the
//      3rd block also fits the VGPR file. Same 12 ds_read_b128 / 128 FMAs.
// 2048 blocks x 512 threads.
// // LDS 46080 B: 3 blocks/CU (was 2 at 54272). 36-float row pad: staged-write
// // banks spread 4/row, ev reads 4 addr x 16-lane broadcast, conflict-free.
// ---------------------------------------------------------------------------
__global__ __launch_bounds__(512, 6) void edge_agg(
    const float* __restrict__ A,         // [B,N,N]
    const float* __restrict__ emb_edge,  // [B,N,N,32]
    const float* __restrict__ W_edge,    // [32,64]
    const float* __restrict__ b_edge,    // [64]
    float* __restrict__ node_out,        // [B,N,64]
    float* __restrict__ edge_out)        // [B,N,N,64]
{
    __shared__ __align__(16) unsigned char smem[36864 + 8192 + 1024];
    float* sE = (float*)smem;                         // [256][36]
    float* sW = (float*)(smem + 36864);               // [32][64]  (GEMM phase)
    float (*sRed)[64] = (float (*)[64])(smem + 36864);// [32][64]  (reduce phase)
    float* sA = (float*)(smem + 36864 + 8192);        // [256]

    const int tid = threadIdx.x;
    const int bn  = blockIdx.x;       // 0..2047 == b*256+n
    const int b   = bn >> 8;

    // ---- stage emb_edge rows for this (b,n): 8192 floats = 2048 f4 ----
    const float* embBase = emb_edge + (size_t)bn * (NN * INE);
#pragma unroll
    for (int it = 0; it < 4; ++it) {
        const int i  = tid + it * 512;
        const f4   v = __builtin_nontemporal_load(((const f4*)embBase) + i);
        const int m  = i >> 3;        // 8 f4 per 32-float row
        const int k4 = i & 7;
        *(f4*)&sE[m * 36 + k4 * 4] = v;
    }
    // ---- stage W_edge (512 f4) and A row (64 f4) ----
    ((f4*)sW)[tid] = ((const f4*)W_edge)[tid];
    if (tid < 64) ((f4*)sA)[tid] = ((const f4*)(A + bn * NN))[tid];
    __syncthreads();

    const int fg = tid & 15;          // 16 f-groups of 4
    const int mg = tid >> 4;          // 32 m-groups (rows mg, mg+32, ..., mg+224)
    const int f0 = fg * 4;

    const f4 bias = *(const f4*)(b_edge + f0);
    float acc[8][4];
#pragma unroll
    for (int i = 0; i < 8; ++i) {
        acc[i][0] = bias.x; acc[i][1] = bias.y; acc[i][2] = bias.z; acc[i][3] = bias.w;
    }

    // ---- register-tiled GEMM: per k-chunk, 12 ds_read_b128 feed 128 FMAs ----
    // w[4] transient per k4 (16 VGPR) instead of ev[8] (32 VGPR): lower peak
    // register pressure so 6 waves/EU fit; identical LDS traffic.
#pragma unroll
    for (int k4 = 0; k4 < 8; ++k4) {
        f4 w[4];
#pragma unroll
        for (int kk = 0; kk < 4; ++kk)
            w[kk] = *(const f4*)&sW[(k4 * 4 + kk) * 64 + f0];
#pragma unroll
        for (int i = 0; i < 8; ++i) {
            const f4 e = *(const f4*)&sE[(mg + i * 32) * 36 + k4 * 4];
#pragma unroll
            for (int kk = 0; kk < 4; ++kk) {
                const float ev = (kk == 0) ? e.x
                               : (kk == 1) ? e.y
                               : (kk == 2) ? e.z
                                           : e.w;
                acc[i][0] = fmaf(ev, w[kk].x, acc[i][0]);
                acc[i][1] = fmaf(ev, w[kk].y, acc[i][1]);
                acc[i][2] = fmaf(ev, w[kk].z, acc[i][2]);
                acc[i][3] = fmaf(ev, w[kk].w, acc[i][3]);
            }
        }
    }

    // ---- epilogue: relu-store edge_out, accumulate agg against node_x ----
    const float* nx = g_node_x + b * (NN * OUTF);
    const size_t outBase = (size_t)bn * (NN * OUTF);
    float agg0 = 0.f, agg1 = 0.f, agg2 = 0.f, agg3 = 0.f;
#pragma unroll
    for (int i = 0; i < 8; ++i) {
        const int m = mg + i * 32;
        const float a = sA[m];                          // broadcast
        const f4 nxv = *(const f4*)&nx[m * 64 + f0];    // L2-hot
        f4 st;
        st.x = fmaxf(acc[i][0], 0.f);
        st.y = fmaxf(acc[i][1], 0.f);
        st.z = fmaxf(acc[i][2], 0.f);
        st.w = fmaxf(acc[i][3], 0.f);
        __builtin_nontemporal_store(st, (f4*)&edge_out[outBase + (size_t)m * 64 + f0]);
        // agg uses PRE-relu edge_x and PRE-relu node_x
        agg0 = fmaf(a * acc[i][0], nxv.x, agg0);
        agg1 = fmaf(a * acc[i][1], nxv.y, agg1);
        agg2 = fmaf(a * acc[i][2], nxv.z, agg2);
        agg3 = fmaf(a * acc[i][3], nxv.w, agg3);
    }

    // sRed aliases sW: fence all sW reads (GEMM done in every wave) first.
    __syncthreads();
    f4 aggv; aggv.x = agg0; aggv.y = agg1; aggv.z = agg2; aggv.w = agg3;
    *(f4*)&sRed[mg][f0] = aggv;
    __syncthreads();

    // ---- reduce 32 m-group partials, add relu(node_sx), store node_out ----
    if (tid < 64) {
        float s = 0.f;
#pragma unroll
        for (int g = 0; g < 32; ++g) s += sRed[g][tid];
        node_out[bn * 64 + tid] = fmaxf(s, 0.f) + g_relu_sx[bn * 64 + tid];
    }
}

// ---------------------------------------------------------------------------
extern "C" void kernel_launch(void* const* d_in, const int* in_sizes, int n_in,
                              void* d_out, int out_size, void* d_ws, size_t ws_size,
                              hipStream_t stream) {
    const float* A        = (const float*)d_in[0];
    const float* emb_node = (const float*)d_in[1];
    const float* emb_edge = (const float*)d_in[2];
    const float* W_node   = (const float*)d_in[3];
    const float* b_node   = (const float*)d_in[4];
    const float* W_nodes  = (const float*)d_in[5];
    const float* b_nodes  = (const float*)d_in[6];
    const float* W_edge   = (const float*)d_in[7];
    const float* b_edge   = (const float*)d_in[8];

    float* node_out = (float*)d_out;                 // [8,256,64]
    float* edge_out = node_out + BB * NN * OUTF;     // [8,256,256,64]

    node_proj<<<(BB * NN) / 4, 256, 0, stream>>>(emb_node, W_node, b_node, W_nodes, b_nodes);
    edge_agg<<<BB * NN, 512, 0, stream>>>(A, emb_edge, W_edge, b_edge, node_out, edge_out);
}